// Round 1
// baseline (251.360 us; speedup 1.0000x reference)
//
#include <hip/hip_runtime.h>
#include <math.h>

// Problem constants (match reference setup_inputs)
constexpr int B = 128, T = 128, F = 2048, KW = 5;
#define ALPHA 0.9f
#define BETA  0.1f
#define DECAY 0.9f
#define GAMMA 0.5f

// One thread per (b,f) series. Lanes consecutive in f -> coalesced at each t.
// conv[t] kept in registers via fully-unrolled loops (static indexing).
__global__ __launch_bounds__(256) void lif_fused_kernel(
    const float* __restrict__ x,        // [B,T,F]
    const float* __restrict__ thr0p,    // scalar
    const float* __restrict__ convw,    // [1,1,KW]
    const float* __restrict__ convb,    // [1]
    const float* __restrict__ sattn,    // [1]
    float* __restrict__ out)            // [B*T*F] spikes ++ [B*F] mem
{
    const int tid = blockIdx.x * blockDim.x + threadIdx.x;
    const int f = tid & (F - 1);
    const int b = tid >> 11;            // tid / F, F = 2048

    const float w0 = convw[0], w1 = convw[1], w2 = convw[2],
                w3 = convw[3], w4 = convw[4];
    const float cb   = convb[0];
    const float thr0 = thr0p[0];
    const float sa   = sattn[0];

    const float* xp = x + (size_t)b * T * F + f;

    // ---- pass over time: 5-tap 'SAME' conv (cross-correlation, zero pad) ----
    float conv[T];
    float sum = 0.0f;
    // window registers: a=x[t-2], bb=x[t-1], c=x[t], d=x[t+1], e=x[t+2]
    float a = 0.0f, bb = 0.0f, c = xp[0], d = xp[(size_t)F];
#pragma unroll
    for (int t = 0; t < T; ++t) {
        float e = (t + 2 < T) ? xp[(size_t)(t + 2) * F] : 0.0f;
        float ct = fmaf(w0, a,
                   fmaf(w1, bb,
                   fmaf(w2, c,
                   fmaf(w3, d,
                   fmaf(w4, e, cb)))));
        conv[t] = ct;
        sum += ct;
        a = bb; bb = c; c = d; d = e;
    }

    // ---- spatial attention gate (uniform scale for this (b,f) series) ----
    const float meanv = sum * (1.0f / (float)T);
    const float z     = sa * meanv;
    const float watt  = 1.0f / (1.0f + expf(-z));
    const float scale = 1.0f + GAMMA * watt;

    // ---- LIF recurrence over time ----
    const float PI = 3.14159265358979323846f;
    float mem = 0.0f, thr = thr0;
    float h0 = 0.0f, h1 = 0.0f, h2 = 0.0f;
    float* sp = out + (size_t)b * T * F + f;               // spikes [B,T,F]
    float* mp = out + (size_t)B * T * F + (size_t)b * F + f; // mem [B,F]

#pragma unroll
    for (int t = 0; t < T; ++t) {
        mem = fmaf(DECAY, mem, conv[t] * scale);
        float sarg  = PI * (mem - thr) * 0.5f;
        float spike = 0.5f * (atanf(sarg) * (1.0f / PI) + 0.5f);
        // hist = [h1, h2, spike]; avg includes the new spike
        h0 = h1; h1 = h2; h2 = spike;
        float avg = (h0 + h1 + h2) * (1.0f / 3.0f);
        thr = fmaf(ALPHA, thr, fmaf(BETA, avg, (1.0f - ALPHA) * thr0));
        mem = fmaf(-spike, thr, mem);
        sp[(size_t)t * F] = spike;
    }
    *mp = mem;
}

extern "C" void kernel_launch(void* const* d_in, const int* in_sizes, int n_in,
                              void* d_out, int out_size, void* d_ws, size_t ws_size,
                              hipStream_t stream) {
    const float* x     = (const float*)d_in[0];
    const float* thr0  = (const float*)d_in[1];
    const float* convw = (const float*)d_in[2];
    const float* convb = (const float*)d_in[3];
    const float* sattn = (const float*)d_in[4];
    float* out = (float*)d_out;

    const int total = B * F;            // one thread per (b,f)
    const int block = 256;
    const int grid  = total / block;    // 1024 blocks

    lif_fused_kernel<<<grid, block, 0, stream>>>(x, thr0, convw, convb, sattn, out);
}